// Round 1
// baseline (471.928 us; speedup 1.0000x reference)
//
#include <hip/hip_runtime.h>
#include <hip/hip_bf16.h>

typedef __bf16 v8bf __attribute__((ext_vector_type(8)));
typedef float  v4f  __attribute__((ext_vector_type(4)));

namespace {
constexpr int C    = 256;
constexpr int L    = 8192;
constexpr int LT   = 64;    // l-tile per block
constexpr int LDXs = 264;   // bf16 row stride (256 + 8 pad) -> conflict-free b128 reads
constexpr int LDYs = 260;   // f32 row stride for y tile
constexpr int NBLK = 1024;
constexpr int TPB_TILES = 4;  // 4096 tiles total / 1024 blocks
}

// block = 256 threads (4 waves). Wave w owns output channels o in [64w, 64w+64).
// MFMA 16x16x32 bf16: A = x^T tile (m=l), B = BN-folded W (n=o), so C/D cols map
// to o -> coalesced stores. W fragments persist in VGPRs across the 4-tile loop.
__global__ __launch_bounds__(256, 2)
void caps_fused(const float* __restrict__ xg, const float* __restrict__ Wg,
                const float* __restrict__ bg, const float* __restrict__ gg,
                const float* __restrict__ betag, const float* __restrict__ mg,
                const float* __restrict__ vg, float* __restrict__ outg)
{
    __shared__ union SU {
        unsigned short xs[LT * LDXs];   // 33792 B  bf16 x^T tile [l][c]
        float          ys[LT * LDYs];   // 66560 B  f32 y tile [l][o]  (aliases xs)
    } U;
    __shared__ float scl[LT];

    const int t    = threadIdx.x;
    const int w    = t >> 6;
    const int ln   = t & 63;
    const int ln15 = ln & 15;
    const int lhi  = ln >> 4;

    // ---- fold BN into W (bf16 fragments) and bias; persistent in registers ----
    v8bf  wf[8][4];     // [kb][ni] : B-frag lane layout n=ln15, k=8*lhi+j
    float bias_f[4];
#pragma unroll
    for (int ni = 0; ni < 4; ++ni) {
        const int o = w * 64 + ni * 16 + ln15;
        const float inv = gg[o] * rsqrtf(vg[o] + 1e-5f);
        bias_f[ni] = bg[o] * inv + betag[o] - mg[o] * inv;
#pragma unroll
        for (int kb = 0; kb < 8; ++kb) {
            const float* wp = Wg + o * C + kb * 32 + lhi * 8;
            const float4 wa = *(const float4*)wp;
            const float4 wb = *(const float4*)(wp + 4);
            union { v8bf v; __hip_bfloat16 h[8]; } fu;
            fu.h[0] = __float2bfloat16(wa.x * inv);
            fu.h[1] = __float2bfloat16(wa.y * inv);
            fu.h[2] = __float2bfloat16(wa.z * inv);
            fu.h[3] = __float2bfloat16(wa.w * inv);
            fu.h[4] = __float2bfloat16(wb.x * inv);
            fu.h[5] = __float2bfloat16(wb.y * inv);
            fu.h[6] = __float2bfloat16(wb.z * inv);
            fu.h[7] = __float2bfloat16(wb.w * inv);
            wf[kb][ni] = fu.v;
        }
    }

    for (int ti = 0; ti < TPB_TILES; ++ti) {
        const int tile = blockIdx.x * TPB_TILES + ti;
        const int b    = tile >> 7;          // 128 l-tiles per batch
        const int l0   = (tile & 127) << 6;
        const float* xb = xg + (size_t)b * C * L + l0;
        float*       ob = outg + ((size_t)b * L + l0) * C;

        __syncthreads();   // previous tile's ys/scl consumers done before xs overwrite

        // ---- stage x tile -> LDS, transposed to [l][c] bf16 ----
        {
            const int lq = (t & 15) * 4;   // base l row (4 rows per thread)
            const int cg = t >> 4;         // 0..15
#pragma unroll
            for (int it = 0; it < 4; ++it) {
                const int c0 = cg * 4 + it * 64;
                float4 f[4];
#pragma unroll
                for (int j = 0; j < 4; ++j)
                    f[j] = *(const float4*)(xb + (size_t)(c0 + j) * L + lq);
#pragma unroll
                for (int i = 0; i < 4; ++i) {
                    union { unsigned long long u; __hip_bfloat16 h[4]; } p;
                    p.h[0] = __float2bfloat16(((const float*)&f[0])[i]);
                    p.h[1] = __float2bfloat16(((const float*)&f[1])[i]);
                    p.h[2] = __float2bfloat16(((const float*)&f[2])[i]);
                    p.h[3] = __float2bfloat16(((const float*)&f[3])[i]);
                    *(unsigned long long*)&U.xs[(lq + i) * LDXs + c0] = p.u;
                }
            }
        }
        __syncthreads();

        // ---- K-loop: 8 steps of K=32, 16 MFMA per wave per step ----
        v4f acc[4][4];
        const v4f vzero = {0.f, 0.f, 0.f, 0.f};
#pragma unroll
        for (int mi = 0; mi < 4; ++mi)
#pragma unroll
            for (int ni = 0; ni < 4; ++ni)
                acc[mi][ni] = vzero;

#pragma unroll
        for (int kb = 0; kb < 8; ++kb) {
            const int c0 = kb * 32 + lhi * 8;
            v8bf a[4];
#pragma unroll
            for (int mi = 0; mi < 4; ++mi)
                a[mi] = *(const v8bf*)&U.xs[(mi * 16 + ln15) * LDXs + c0];
#pragma unroll
            for (int mi = 0; mi < 4; ++mi)
#pragma unroll
                for (int ni = 0; ni < 4; ++ni)
                    acc[mi][ni] = __builtin_amdgcn_mfma_f32_16x16x32_bf16(
                        a[mi], wf[kb][ni], acc[mi][ni], 0, 0, 0);
        }
        __syncthreads();   // all xs reads done before ys (aliased) is written

        // ---- epilogue: acc + bias -> ys[l][o] ----
#pragma unroll
        for (int mi = 0; mi < 4; ++mi)
#pragma unroll
            for (int ni = 0; ni < 4; ++ni) {
                const int oo = w * 64 + ni * 16 + ln15;
#pragma unroll
                for (int r = 0; r < 4; ++r) {
                    const int l = mi * 16 + lhi * 4 + r;   // C/D: row=(lhi*4+r), col=ln15
                    U.ys[l * LDYs + oo] = acc[mi][ni][r] + bias_f[ni];
                }
            }
        __syncthreads();

        // ---- squash scale per l row: scale = n2 / ((1+n2)(sqrt(n2)+eps)) ----
        {
            const int l = t >> 2, q = t & 3;
            const float* yr = &U.ys[l * LDYs + q * 64];
            float s = 0.f;
#pragma unroll
            for (int i = 0; i < 16; ++i) {
                const float4 v = *(const float4*)(yr + 4 * i);
                s += v.x * v.x + v.y * v.y + v.z * v.z + v.w * v.w;
            }
            s += __shfl_xor(s, 1);
            s += __shfl_xor(s, 2);
            if (q == 0) {
                const float n = sqrtf(s);
                scl[l] = s / ((1.f + s) * (n + 1e-8f));
            }
        }
        __syncthreads();

        // ---- scaled store: one wave per l row -> 1 KB contiguous per instr ----
        {
            const int o4 = ln * 4;
#pragma unroll
            for (int rb = 0; rb < 16; ++rb) {
                const int l  = rb * 4 + w;
                const float sc = scl[l];
                float4 v = *(const float4*)&U.ys[l * LDYs + o4];
                v.x *= sc; v.y *= sc; v.z *= sc; v.w *= sc;
                *(float4*)(ob + (size_t)l * C + o4) = v;
            }
        }
    }
}

extern "C" void kernel_launch(void* const* d_in, const int* in_sizes, int n_in,
                              void* d_out, int out_size, void* d_ws, size_t ws_size,
                              hipStream_t stream)
{
    const float* x     = (const float*)d_in[0];
    const float* W     = (const float*)d_in[1];
    const float* b     = (const float*)d_in[2];
    const float* gamma = (const float*)d_in[3];
    const float* beta  = (const float*)d_in[4];
    const float* mean  = (const float*)d_in[5];
    const float* var   = (const float*)d_in[6];
    float* out = (float*)d_out;

    hipLaunchKernelGGL(caps_fused, dim3(NBLK), dim3(256), 0, stream,
                       x, W, b, gamma, beta, mean, var, out);
}